// Round 1
// baseline (3795.377 us; speedup 1.0000x reference)
//
#include <hip/hip_runtime.h>

typedef __attribute__((ext_vector_type(8))) short short8;
typedef __attribute__((ext_vector_type(4))) float f32x4;

#define DEV static __device__ __forceinline__

DEV unsigned short f2bf(float x) {
  unsigned u = __float_as_uint(x);
  return (unsigned short)((u + 0x7fffu + ((u >> 16) & 1u)) >> 16);
}
DEV float bf2f(unsigned short h) { return __uint_as_float(((unsigned)h) << 16); }

// ---------------- prep: stable descending argsort + gathers ----------------
__global__ void k_prep(const int* __restrict__ cap_len, const int* __restrict__ captions,
                       int* __restrict__ sind, int* __restrict__ dlen, int* __restrict__ emb_rows,
                       float* __restrict__ out_caps, float* __restrict__ out_dlen,
                       float* __restrict__ out_sind) {
  __shared__ int lens[64];
  __shared__ int ssind[64];
  int i = threadIdx.x;
  lens[i] = cap_len[i];
  __syncthreads();
  int li = lens[i];
  int rank = 0;
  for (int j = 0; j < 64; ++j) {
    int lj = lens[j];
    rank += (lj > li || (lj == li && j < i)) ? 1 : 0;
  }
  ssind[rank] = i;
  __syncthreads();
  int b = i;
  int s = ssind[b];
  sind[b] = s;
  int dl = lens[s] - 1;
  dlen[b] = dl;
  out_dlen[b] = (float)dl;
  out_sind[b] = (float)s;
  for (int l = 0; l < 22; ++l) {
    int cv = captions[s * 22 + l];
    out_caps[b * 22 + l] = (float)cv;
    if (l < 21) emb_rows[l * 64 + b] = cv;
  }
}

// ---------------- gather sorted encoder rows -> bf16 ----------------
__global__ __launch_bounds__(256) void k_gather_enc(const float* __restrict__ enc,
                                                    const int* __restrict__ sind,
                                                    unsigned short* __restrict__ dst) {
  int bp = blockIdx.x;            // 0..12543
  int b = bp / 196, p = bp % 196;
  const float* src = enc + ((size_t)sind[b] * 196 + p) * 2048 + threadIdx.x * 8;
  float4 v0 = *(const float4*)src;
  float4 v1 = *(const float4*)(src + 4);
  uint4 o;
  o.x = f2bf(v0.x) | ((unsigned)f2bf(v0.y) << 16);
  o.y = f2bf(v0.z) | ((unsigned)f2bf(v0.w) << 16);
  o.z = f2bf(v1.x) | ((unsigned)f2bf(v1.y) << 16);
  o.w = f2bf(v1.z) | ((unsigned)f2bf(v1.w) << 16);
  *(uint4*)(dst + (size_t)bp * 2048 + threadIdx.x * 8) = o;
}

// ---------------- flat f32 -> bf16 ----------------
__global__ __launch_bounds__(256) void k_convert(const float* __restrict__ src,
                                                 unsigned short* __restrict__ dst, int n8) {
  int i = blockIdx.x * 256 + threadIdx.x;
  if (i >= n8) return;
  float4 v0 = *(const float4*)(src + (size_t)i * 8);
  float4 v1 = *(const float4*)(src + (size_t)i * 8 + 4);
  uint4 o;
  o.x = f2bf(v0.x) | ((unsigned)f2bf(v0.y) << 16);
  o.y = f2bf(v0.z) | ((unsigned)f2bf(v0.w) << 16);
  o.z = f2bf(v1.x) | ((unsigned)f2bf(v1.y) << 16);
  o.w = f2bf(v1.z) | ((unsigned)f2bf(v1.w) << 16);
  *(uint4*)(dst + (size_t)i * 8) = o;
}

// ---------------- gather embedding rows -> bf16 A matrix [1344][512] ----------------
__global__ __launch_bounds__(256) void k_gather_emb(const float* __restrict__ emb,
                                                    const int* __restrict__ rows,
                                                    unsigned short* __restrict__ dst) {
  int r = blockIdx.x;
  const float* s = emb + (size_t)rows[r] * 512;
  unsigned short* d = dst + (size_t)r * 512;
  int t = threadIdx.x;
  d[t] = f2bf(s[t]);
  d[t + 256] = f2bf(s[t + 256]);
}

// ---------------- mean over 196 pixels (sorted gather) ----------------
__global__ __launch_bounds__(256) void k_mean(const float* __restrict__ enc,
                                              const int* __restrict__ sind,
                                              float* __restrict__ mean) {
  int b = blockIdx.x;
  int e = blockIdx.y * 256 + threadIdx.x;
  const float* base = enc + ((size_t)sind[b] * 196) * 2048 + e;
  float s = 0.f;
  for (int p = 0; p < 196; ++p) s += base[(size_t)p * 2048];
  mean[b * 2048 + e] = s * (1.0f / 196.0f);
}

// ---------------- h0/c0 init GEMV ----------------
__global__ __launch_bounds__(256) void k_init(const float* __restrict__ mean,
                                              const float* __restrict__ Wh, const float* __restrict__ bh,
                                              const float* __restrict__ Wc, const float* __restrict__ bc,
                                              float* __restrict__ h, float* __restrict__ c) {
  int b = blockIdx.x;
  int j = blockIdx.y * 256 + threadIdx.x;
  __shared__ float me[2048];
  for (int i = threadIdx.x; i < 2048; i += 256) me[i] = mean[b * 2048 + i];
  __syncthreads();
  float ah = bh[j], ac = bc[j];
  for (int k = 0; k < 2048; ++k) {
    float mv = me[k];
    ah += mv * Wh[(size_t)k * 512 + j];
    ac += mv * Wc[(size_t)k * 512 + j];
  }
  h[b * 512 + j] = ah;
  c[b * 512 + j] = ac;
}

// ---------------- bf16 MFMA GEMM: C[M][N] = A[M][K] @ B[K][N] (+bias) ----------------
// tile 64x128, 4 waves (each 64x32), BK=32, 16x16x32 bf16 MFMA.
// mode 0: f32 out (Cf). mode 1: bf16 out (Cb). mode 2: FC epilogue (permute+mask) into Cf.
__global__ __launch_bounds__(256) void k_gemm(const unsigned short* __restrict__ A,
                                              const unsigned short* __restrict__ B,
                                              const float* __restrict__ bias1,
                                              const float* __restrict__ bias2,
                                              float* __restrict__ Cf,
                                              unsigned short* __restrict__ Cb,
                                              const int* __restrict__ dlen,
                                              int M, int N, int K, int mode) {
  __shared__ unsigned short As[64][40];
  __shared__ unsigned short Bs[128][40];   // transposed: [n][k]
  int t = threadIdx.x;
  int lane = t & 63, w = t >> 6;
  int m0 = blockIdx.y * 64, n0 = blockIdx.x * 128;
  f32x4 acc[4][2] = {};
  int arow = t >> 2, ak8 = (t & 3) * 8;
  int bk2 = (t >> 4) * 2, bnc = (t & 15) * 8;
  for (int kc = 0; kc < K; kc += 32) {
    __syncthreads();
    uint4 av = *(const uint4*)(A + (size_t)(m0 + arow) * K + kc + ak8);
    *(uint4*)&As[arow][ak8] = av;
    uint4 b0 = *(const uint4*)(B + (size_t)(kc + bk2) * N + n0 + bnc);
    uint4 b1 = *(const uint4*)(B + (size_t)(kc + bk2 + 1) * N + n0 + bnc);
    const unsigned short* p0 = (const unsigned short*)&b0;
    const unsigned short* p1 = (const unsigned short*)&b1;
#pragma unroll
    for (int j = 0; j < 8; ++j) {
      *(unsigned*)&Bs[bnc + j][bk2] = (unsigned)p0[j] | ((unsigned)p1[j] << 16);
    }
    __syncthreads();
    short8 a[4], bf[2];
#pragma unroll
    for (int mi = 0; mi < 4; ++mi)
      a[mi] = *(const short8*)&As[mi * 16 + (lane & 15)][(lane >> 4) * 8];
#pragma unroll
    for (int ni = 0; ni < 2; ++ni)
      bf[ni] = *(const short8*)&Bs[w * 32 + ni * 16 + (lane & 15)][(lane >> 4) * 8];
#pragma unroll
    for (int mi = 0; mi < 4; ++mi)
#pragma unroll
      for (int ni = 0; ni < 2; ++ni)
        acc[mi][ni] = __builtin_amdgcn_mfma_f32_16x16x32_bf16(a[mi], bf[ni], acc[mi][ni], 0, 0, 0);
  }
  int rbase = (lane >> 4) * 4;
  int cbase = n0 + w * 32 + (lane & 15);
#pragma unroll
  for (int mi = 0; mi < 4; ++mi) {
#pragma unroll
    for (int ni = 0; ni < 2; ++ni) {
      int n = cbase + ni * 16;
      float badd = (bias1 ? bias1[n] : 0.f) + (bias2 ? bias2[n] : 0.f);
#pragma unroll
      for (int r = 0; r < 4; ++r) {
        int m = m0 + mi * 16 + rbase + r;
        float v = acc[mi][ni][r] + badd;
        if (mode == 0) {
          Cf[(size_t)m * N + n] = v;
        } else if (mode == 1) {
          Cb[(size_t)m * N + n] = f2bf(v);
        } else {
          int tt = m >> 6, bb = m & 63;
          Cf[(size_t)bb * 672000 + (size_t)tt * 32000 + n] = (tt < dlen[bb]) ? v : 0.f;
        }
      }
    }
  }
}

// ---------------- fused per-step attention: d_att + gate + e + softmax ----------------
__global__ __launch_bounds__(256) void k_att(const float* __restrict__ h,
                                             const unsigned short* __restrict__ pre_att,
                                             const float* __restrict__ Wd, const float* __restrict__ bd,
                                             const float* __restrict__ v_att,
                                             const float* __restrict__ Wb, const float* __restrict__ bb,
                                             float* __restrict__ alpha, float* __restrict__ gatev) {
  int b = blockIdx.x, t = threadIdx.x;
  __shared__ float hld[512], datt[512], eld[200], red[256];
  hld[t] = h[b * 512 + t];
  hld[t + 256] = h[b * 512 + 256 + t];
  __syncthreads();
#pragma unroll
  for (int jj = 0; jj < 2; ++jj) {
    int j = jj * 256 + t;
    float a = bd[j];
    for (int k = 0; k < 512; ++k) a += hld[k] * Wd[k * 512 + j];
    datt[j] = a;
  }
  red[t] = hld[t] * Wb[t] + hld[t + 256] * Wb[t + 256];
  __syncthreads();
  for (int s = 128; s > 0; s >>= 1) { if (t < s) red[t] += red[t + s]; __syncthreads(); }
  float gate = red[0] + bb[0];
  int w = t >> 6, lane = t & 63;
  for (int p = w; p < 196; p += 4) {
    const unsigned short* pa = pre_att + ((size_t)(b * 196 + p)) * 512;
    float acc = 0.f;
#pragma unroll
    for (int a0 = 0; a0 < 512; a0 += 128) {
      int ai = a0 + lane * 2;
      unsigned u = *(const unsigned*)(pa + ai);
      float p0 = bf2f((unsigned short)(u & 0xffffu)) + datt[ai];
      float p1 = bf2f((unsigned short)(u >> 16)) + datt[ai + 1];
      p0 = fmaxf(p0, 0.f);
      p1 = fmaxf(p1, 0.f);
      acc += p0 * v_att[ai] + p1 * v_att[ai + 1];
    }
#pragma unroll
    for (int off = 32; off > 0; off >>= 1) acc += __shfl_down(acc, off, 64);
    if (lane == 0) eld[p] = acc;
  }
  __syncthreads();
  red[t] = (t < 196) ? eld[t] : -3.4e38f;
  __syncthreads();
  for (int s = 128; s > 0; s >>= 1) { if (t < s) red[t] = fmaxf(red[t], red[t + s]); __syncthreads(); }
  float mx = red[0];
  __syncthreads();
  float ex = (t < 196) ? expf(eld[t] - mx) : 0.f;
  red[t] = ex;
  __syncthreads();
  for (int s = 128; s > 0; s >>= 1) { if (t < s) red[t] += red[t + s]; __syncthreads(); }
  float inv = 1.f / red[0];
  if (t < 196) alpha[b * 196 + t] = ex * inv;
  if (t == 0) gatev[b] = gate;
}

// ---------------- z = gate * (alpha @ enc_s) ----------------
__global__ __launch_bounds__(256) void k_z(const float* __restrict__ alpha,
                                           const float* __restrict__ gatev,
                                           const unsigned short* __restrict__ encb,
                                           float* __restrict__ z) {
  int b = blockIdx.x, t = threadIdx.x;
  __shared__ float ald[196];
  if (t < 196) ald[t] = alpha[b * 196 + t];
  __syncthreads();
  int e0 = blockIdx.y * 1024 + t * 4;
  const unsigned short* base = encb + (size_t)b * 196 * 2048 + e0;
  float a0 = 0, a1 = 0, a2 = 0, a3 = 0;
#pragma unroll 4
  for (int p = 0; p < 196; ++p) {
    uint2 v = *(const uint2*)(base + (size_t)p * 2048);
    float al = ald[p];
    a0 += al * bf2f((unsigned short)(v.x & 0xffffu));
    a1 += al * bf2f((unsigned short)(v.x >> 16));
    a2 += al * bf2f((unsigned short)(v.y & 0xffffu));
    a3 += al * bf2f((unsigned short)(v.y >> 16));
  }
  float g = gatev[b];
  float* zp = z + (size_t)b * 2048 + e0;
  zp[0] = g * a0;
  zp[1] = g * a1;
  zp[2] = g * a2;
  zp[3] = g * a3;
}

// ---------------- LSTM gates: gates = ge[t] + z @ W_ih[512:] + h @ W_hh ----------------
// grid 128 blocks (n-chunk 16), block computes all 64 b x 16 n.
__global__ __launch_bounds__(256) void k_gates(const float* __restrict__ z, const float* __restrict__ h,
                                               const float* __restrict__ W_ih, const float* __restrict__ W_hh,
                                               const float* __restrict__ ge, float* __restrict__ gates,
                                               int step) {
  __shared__ float Xs[64][68];
  __shared__ float Ws[64][20];
  int t = threadIdx.x;
  int n0 = blockIdx.x * 16;
  int bIdx = t >> 2, nIdx = t & 3;
  float acc0 = 0, acc1 = 0, acc2 = 0, acc3 = 0;
  int srow = t >> 2, skk0 = (t & 3) * 16;
  int wrow = t >> 2, wnn0 = (t & 3) * 4;
  for (int kc = 0; kc < 40; ++kc) {
    int kglob = kc * 64;
    __syncthreads();
    const float* xsrc = (kglob < 2048) ? (z + (size_t)srow * 2048 + kglob + skk0)
                                       : (h + (size_t)srow * 512 + (kglob - 2048) + skk0);
#pragma unroll
    for (int i = 0; i < 4; ++i) {
      float4 v = *(const float4*)(xsrc + i * 4);
      *(float4*)&Xs[srow][skk0 + i * 4] = v;
    }
    const float* wsrc = (kglob < 2048)
                            ? (W_ih + ((size_t)(512 + kglob + wrow)) * 2048 + n0 + wnn0)
                            : (W_hh + ((size_t)(kglob - 2048 + wrow)) * 2048 + n0 + wnn0);
    float4 wv = *(const float4*)wsrc;
    *(float4*)&Ws[wrow][wnn0] = wv;
    __syncthreads();
#pragma unroll
    for (int kk = 0; kk < 64; ++kk) {
      float x = Xs[bIdx][kk];
      float4 wr = *(const float4*)&Ws[kk][nIdx * 4];
      acc0 += x * wr.x;
      acc1 += x * wr.y;
      acc2 += x * wr.z;
      acc3 += x * wr.w;
    }
  }
  int n = n0 + nIdx * 4;
  const float* gep = ge + ((size_t)step * 64 + bIdx) * 2048 + n;
  float* gp = gates + (size_t)bIdx * 2048 + n;
  gp[0] = acc0 + gep[0];
  gp[1] = acc1 + gep[1];
  gp[2] = acc2 + gep[2];
  gp[3] = acc3 + gep[3];
}

// ---------------- LSTM cell elementwise ----------------
__global__ __launch_bounds__(256) void k_cell(const float* __restrict__ gates,
                                              const int* __restrict__ dlen,
                                              float* __restrict__ h, float* __restrict__ c,
                                              unsigned short* __restrict__ h_all, int step) {
  int idx = blockIdx.x * 256 + threadIdx.x;  // 0..32767
  int b = idx >> 9, j = idx & 511;
  const float* g = gates + (size_t)b * 2048;
  float gi = g[j], gf = g[512 + j], gg = g[1024 + j], go = g[1536 + j];
  float si = 1.f / (1.f + expf(-gi));
  float sf = 1.f / (1.f + expf(-gf));
  float so = 1.f / (1.f + expf(-go));
  float cold = c[idx];
  float cn = sf * cold + si * tanhf(gg);
  float hn = so * tanhf(cn);
  bool m = step < dlen[b];
  h[idx] = m ? hn : h[idx];
  c[idx] = m ? cn : cold;
  h_all[((size_t)step * 64 + b) * 512 + j] = f2bf(hn);
}

extern "C" void kernel_launch(void* const* d_in, const int* in_sizes, int n_in,
                              void* d_out, int out_size, void* d_ws, size_t ws_size,
                              hipStream_t stream) {
  (void)in_sizes; (void)n_in; (void)out_size; (void)ws_size;
  const float* enc = (const float*)d_in[0];
  const int* captions = (const int*)d_in[1];
  const int* cap_len = (const int*)d_in[2];
  const float* emb = (const float*)d_in[3];
  const float* We_att = (const float*)d_in[4];
  const float* be_att = (const float*)d_in[5];
  const float* Wd_att = (const float*)d_in[6];
  const float* bd_att = (const float*)d_in[7];
  const float* v_att = (const float*)d_in[8];
  const float* W_beta = (const float*)d_in[10];
  const float* b_beta = (const float*)d_in[11];
  const float* W_ih = (const float*)d_in[12];
  const float* b_ih = (const float*)d_in[13];
  const float* W_hh = (const float*)d_in[14];
  const float* b_hh = (const float*)d_in[15];
  const float* W_init_h = (const float*)d_in[16];
  const float* b_init_h = (const float*)d_in[17];
  const float* W_init_c = (const float*)d_in[18];
  const float* b_init_c = (const float*)d_in[19];
  const float* W_fc = (const float*)d_in[20];
  const float* b_fc = (const float*)d_in[21];

  float* out = (float*)d_out;
  float* out_pred = out;              // 64*21*32000
  float* out_caps = out + 43008000;   // 1408
  float* out_dlen = out + 43009408;   // 64
  float* out_alph = out + 43009472;   // 263424
  float* out_sind = out + 43272896;   // 64

  char* ws = (char*)d_ws;
  size_t off = 0;
  auto alloc = [&](size_t bytes) -> void* {
    off = (off + 255) & ~(size_t)255;
    void* p = ws + off;
    off += bytes;
    return p;
  };
  int* sind = (int*)alloc(64 * 4);
  int* dlen = (int*)alloc(64 * 4);
  int* emb_rows = (int*)alloc(1344 * 4);
  unsigned short* enc_b = (unsigned short*)alloc((size_t)25690112 * 2);
  unsigned short* Weatt_b = (unsigned short*)alloc((size_t)1048576 * 2);
  unsigned short* Wih_b = (unsigned short*)alloc((size_t)1048576 * 2);
  unsigned short* Wfc_b = (unsigned short*)alloc((size_t)16384000 * 2);
  unsigned short* Aemb_b = (unsigned short*)alloc((size_t)688128 * 2);
  unsigned short* hall_b = (unsigned short*)alloc((size_t)688128 * 2);
  unsigned short* preatt_b = (unsigned short*)alloc((size_t)6422528 * 2);
  float* ge = (float*)alloc((size_t)2752512 * 4);
  float* meanv = (float*)alloc(131072 * 4);
  float* hbuf = (float*)alloc(32768 * 4);
  float* cbuf = (float*)alloc(32768 * 4);
  float* alpha = (float*)alloc(12544 * 4);
  float* gatev = (float*)alloc(64 * 4);
  float* zbuf = (float*)alloc(131072 * 4);
  float* gates = (float*)alloc(131072 * 4);

  k_prep<<<1, 64, 0, stream>>>(cap_len, captions, sind, dlen, emb_rows, out_caps, out_dlen, out_sind);
  hipMemsetAsync(out_alph, 0, (size_t)263424 * 4, stream);
  k_gather_enc<<<12544, 256, 0, stream>>>(enc, sind, enc_b);
  k_convert<<<(131072 + 255) / 256, 256, 0, stream>>>(We_att, Weatt_b, 131072);
  k_convert<<<(131072 + 255) / 256, 256, 0, stream>>>(W_ih, Wih_b, 131072);      // rows 0..511 only
  k_convert<<<(2048000 + 255) / 256, 256, 0, stream>>>(W_fc, Wfc_b, 2048000);
  k_gather_emb<<<1344, 256, 0, stream>>>(emb, emb_rows, Aemb_b);
  k_mean<<<dim3(64, 8), 256, 0, stream>>>(enc, sind, meanv);
  k_init<<<dim3(64, 2), 256, 0, stream>>>(meanv, W_init_h, b_init_h, W_init_c, b_init_c, hbuf, cbuf);
  // pre_att = enc_s @ We_att + be_att  -> bf16
  k_gemm<<<dim3(4, 196), 256, 0, stream>>>(enc_b, Weatt_b, be_att, nullptr, nullptr, preatt_b,
                                           nullptr, 12544, 512, 2048, 1);
  // gates_emb = emb_seq @ W_ih[0:512] + b_ih + b_hh  -> f32
  k_gemm<<<dim3(16, 21), 256, 0, stream>>>(Aemb_b, Wih_b, b_ih, b_hh, ge, nullptr,
                                           nullptr, 1344, 2048, 512, 0);
  for (int s = 0; s < 21; ++s) {
    k_att<<<64, 256, 0, stream>>>(hbuf, preatt_b, Wd_att, bd_att, v_att, W_beta, b_beta, alpha, gatev);
    k_z<<<dim3(64, 2), 256, 0, stream>>>(alpha, gatev, enc_b, zbuf);
    k_gates<<<128, 256, 0, stream>>>(zbuf, hbuf, W_ih, W_hh, ge, gates, s);
    k_cell<<<128, 256, 0, stream>>>(gates, dlen, hbuf, cbuf, hall_b, s);
  }
  // predictions = mask(h_all @ W_fc + b_fc), permuted to [b][t][v]
  k_gemm<<<dim3(250, 21), 256, 0, stream>>>(hall_b, Wfc_b, b_fc, nullptr, out_pred, nullptr,
                                            dlen, 1344, 32000, 512, 2);
}